// Round 1
// baseline (3977.691 us; speedup 1.0000x reference)
//
#include <hip/hip_runtime.h>
#include <hip/hip_bf16.h>
#include <stdint.h>

typedef unsigned short u16;
typedef short bf16x8 __attribute__((ext_vector_type(8)));
typedef float f32x4 __attribute__((ext_vector_type(4)));

#define H      300
#define KP     320          // K padded to multiple of 32
#define BATCH  256
#define NX     128
#define NY     128
#define VY     32000
#define NPAD   32768        // vocab padded to 8*16*256
#define MROWS  32512        // 127*256 decoder rows

// workspace layout (bytes)
#define OW_OFF   0UL
#define OW_BYTES ((unsigned long)NPAD * KP * 2)        // 20,971,520
#define A_OFF    (OW_OFF + OW_BYTES)
#define A_BYTES  ((unsigned long)MROWS * KP * 2)       // 20,807,680
#define WTE_OFF  (A_OFF + A_BYTES)
#define WT_BYTES ((unsigned long)H * KP * 4)           // 384,000
#define WTD_OFF  (WTE_OFF + WT_BYTES)
#define SE_OFF   (WTD_OFF + WT_BYTES)
#define SE_BYTES ((unsigned long)MROWS * 4)

typedef const __attribute__((address_space(1))) char* gp_t;
typedef __attribute__((address_space(3))) char* lp_t;

// ---------------- K0: prep (bf16-convert outW padded; transpose enc/dec W) --
__global__ __launch_bounds__(256) void k0_prep(const float* __restrict__ outW,
                                               const float* __restrict__ encW,
                                               const float* __restrict__ decW,
                                               __hip_bfloat16* __restrict__ owb,
                                               float* __restrict__ wte,
                                               float* __restrict__ wtd) {
    long id = (long)blockIdx.x * 256 + threadIdx.x;
    const long n1 = (long)NPAD * KP;
    if (id < n1) {
        int v = (int)(id / KP), k = (int)(id % KP);
        float f = (v < VY && k < H) ? outW[v * H + k] : 0.f;
        owb[id] = __float2bfloat16(f);
        return;
    }
    long id2 = id - n1;
    if (id2 < (long)H * KP) {                 // Wt_enc[k][j] = encW[j][k]
        int k = (int)(id2 / KP), j = (int)(id2 % KP);
        wte[id2] = (j < H) ? encW[j * H + k] : 0.f;
        return;
    }
    id2 -= (long)H * KP;
    if (id2 < (long)H * KP) {                 // Wt_dec
        int k = (int)(id2 / KP), j = (int)(id2 % KP);
        wtd[id2] = (j < H) ? decW[j * H + k] : 0.f;
    }
}

// ---------------- K1: fused enc+dec recurrence, batch-parallel (no grid sync)
// 64 blocks x 4 batch elements; h kept fp32 in LDS layout h[k][bi] for float4
// broadcast reads. Decoder h written as bf16 rows (K-padded) to A matrix.
__global__ __launch_bounds__(320) void k1_rnn(const int* __restrict__ x,
                                              const int* __restrict__ y,
                                              const float* __restrict__ enc_emb,
                                              const float* __restrict__ dec_emb,
                                              const float* __restrict__ encb,
                                              const float* __restrict__ decb,
                                              const float* __restrict__ wte,
                                              const float* __restrict__ wtd,
                                              __hip_bfloat16* __restrict__ A) {
    const int j = threadIdx.x;           // output unit (0..319, <300 active)
    const int bb = blockIdx.x * 4;       // batch base
    __shared__ __align__(16) float h[H * 4];   // h[k*4 + bi]
    for (int i = j; i < H * 4; i += 320) h[i] = 0.f;
    __syncthreads();
    const float be = (j < H) ? encb[j] : 0.f;
    const float bd = (j < H) ? decb[j] : 0.f;

    // ---- encoder: 128 steps ----
    for (int t = 0; t < NX; ++t) {
        int i0 = x[t * BATCH + bb + 0], i1 = x[t * BATCH + bb + 1];
        int i2 = x[t * BATCH + bb + 2], i3 = x[t * BATCH + bb + 3];
        float a0 = be, a1 = be, a2 = be, a3 = be;
        if (j < H) {
            a0 += enc_emb[(long)i0 * H + j];
            a1 += enc_emb[(long)i1 * H + j];
            a2 += enc_emb[(long)i2 * H + j];
            a3 += enc_emb[(long)i3 * H + j];
        }
#pragma unroll 4
        for (int k = 0; k < H; ++k) {
            float wt = wte[k * KP + j];
            float4 hv = *(const float4*)&h[k * 4];
            a0 += wt * hv.x; a1 += wt * hv.y; a2 += wt * hv.z; a3 += wt * hv.w;
        }
        __syncthreads();
        if (j < H) {
            float4 nv = { fmaxf(a0, 0.f), fmaxf(a1, 0.f), fmaxf(a2, 0.f), fmaxf(a3, 0.f) };
            *(float4*)&h[j * 4] = nv;
        }
        __syncthreads();
    }

    // ---- decoder: 127 steps; write bf16 h rows into A ----
    for (int t = 0; t < NY - 1; ++t) {
        int i0 = y[t * BATCH + bb + 0], i1 = y[t * BATCH + bb + 1];
        int i2 = y[t * BATCH + bb + 2], i3 = y[t * BATCH + bb + 3];
        float a0 = bd, a1 = bd, a2 = bd, a3 = bd;
        if (j < H) {
            a0 += dec_emb[(long)i0 * H + j];
            a1 += dec_emb[(long)i1 * H + j];
            a2 += dec_emb[(long)i2 * H + j];
            a3 += dec_emb[(long)i3 * H + j];
        }
#pragma unroll 4
        for (int k = 0; k < H; ++k) {
            float wt = wtd[k * KP + j];
            float4 hv = *(const float4*)&h[k * 4];
            a0 += wt * hv.x; a1 += wt * hv.y; a2 += wt * hv.z; a3 += wt * hv.w;
        }
        __syncthreads();
        float4 nv = { fmaxf(a0, 0.f), fmaxf(a1, 0.f), fmaxf(a2, 0.f), fmaxf(a3, 0.f) };
        if (j < H) *(float4*)&h[j * 4] = nv;
        // A rows (nv==0 for j>=300 since wtd pad cols are 0, bd=0, no emb)
        long r0 = (long)t * BATCH + bb;
        A[(r0 + 0) * KP + j] = __float2bfloat16(nv.x);
        A[(r0 + 1) * KP + j] = __float2bfloat16(nv.y);
        A[(r0 + 2) * KP + j] = __float2bfloat16(nv.z);
        A[(r0 + 3) * KP + j] = __float2bfloat16(nv.w);
        __syncthreads();
    }
}

// ---------------- K2: fused logits GEMM + exp row-sum --------------------
// grid = 254 rowblocks * 8 colgroups; colgroup == blockIdx%8 == XCD for L2
// locality of the 2.6MB outW slice. A tile (128x320 bf16) resident in LDS
// (row stride 328 to spread banks); B (256 cols x 32 k) double-buffered via
// global_load_lds width=16.
__global__ __launch_bounds__(512) void k2_gemm(const u16* __restrict__ A,
                                               const u16* __restrict__ OW,
                                               const float* __restrict__ outb,
                                               float* __restrict__ sumexp) {
    const int tid = threadIdx.x;
    const int lane = tid & 63, wave = tid >> 6;
    const int lane16 = lane & 15, quad = lane >> 4;
    const int wr = wave >> 2, wc = wave & 3;     // 2x4 wave grid, 64x64 tiles
    const int cg = blockIdx.x & 7;
    const int rb = blockIdx.x >> 3;

    __shared__ u16 Ald[128 * 328];
    __shared__ u16 Bld[2][8192];
    __shared__ float rowsum[128];
    if (tid < 128) rowsum[tid] = 0.f;

    // stage A tile once: 128 rows x 640B -> LDS stride 656B
    {
        const char* ag = (const char*)(A + (long)rb * 128 * KP);
#pragma unroll
        for (int i = 0; i < 10; ++i) {
            int t2 = i * 512 + tid;
            int row = t2 / 40, o = t2 % 40;
            uint4 v = *(const uint4*)(ag + row * 640 + o * 16);
            *(uint4*)((char*)Ald + row * 656 + o * 16) = v;
        }
    }

    const char* owg = (const char*)OW;
    const int colbase = cg * 4096;

    auto stage = [&](int it, int buf) {
        int ct = it / 10, ks = it - ct * 10;
        int v0 = colbase + ct * 256;
        int col = tid >> 2, kq = tid & 3;
        const char* g1 = owg + (long)(v0 + col) * 640 + ks * 64 + kq * 16;
        const char* g2 = owg + (long)(v0 + 128 + col) * 640 + ks * 64 + kq * 16;
        char* l1 = (char*)&Bld[buf][0] + tid * 16;
        char* l2 = (char*)&Bld[buf][0] + 8192 + tid * 16;
        __builtin_amdgcn_global_load_lds((gp_t)g1, (lp_t)l1, 16, 0, 0);
        __builtin_amdgcn_global_load_lds((gp_t)g2, (lp_t)l2, 16, 0, 0);
    };

    f32x4 acc[4][4];
    float rsum[16];
#pragma unroll
    for (int s = 0; s < 16; ++s) rsum[s] = 0.f;

    stage(0, 0);
    for (int it = 0; it < 160; ++it) {          // 16 col-tiles x 10 k-steps
        int ct = it / 10, ks = it - ct * 10;
        __syncthreads();                         // drains prev stage's loads
        if (it + 1 < 160) stage(it + 1, (it + 1) & 1);
        if (ks == 0) {
#pragma unroll
            for (int a = 0; a < 4; ++a)
#pragma unroll
                for (int b = 0; b < 4; ++b) acc[a][b] = (f32x4){0.f, 0.f, 0.f, 0.f};
        }
        const u16* Bb = &Bld[it & 1][0];
        bf16x8 af[4], bfr[4];
#pragma unroll
        for (int tr = 0; tr < 4; ++tr)
            af[tr] = *(const bf16x8*)&Ald[(wr * 64 + tr * 16 + lane16) * 328 + ks * 32 + quad * 8];
#pragma unroll
        for (int tc = 0; tc < 4; ++tc) {
            int col = wc * 64 + tc * 16 + lane16;
            bfr[tc] = *(const bf16x8*)&Bb[col * 32 + quad * 8];
        }
#pragma unroll
        for (int tr = 0; tr < 4; ++tr)
#pragma unroll
            for (int tc = 0; tc < 4; ++tc)
                acc[tr][tc] = __builtin_amdgcn_mfma_f32_16x16x32_bf16(af[tr], bfr[tc], acc[tr][tc], 0, 0, 0);

        if (ks == 9) {                           // epilogue for this col-tile
            int cb = colbase + ct * 256 + wc * 64;
#pragma unroll
            for (int tc = 0; tc < 4; ++tc) {
                int v = cb + tc * 16 + lane16;
                bool valid = v < VY;
                float ob = valid ? outb[v] : 0.f;
#pragma unroll
                for (int tr = 0; tr < 4; ++tr)
#pragma unroll
                    for (int i = 0; i < 4; ++i) {
                        float lg = acc[tr][tc][i] + ob;
                        if (valid) rsum[tr * 4 + i] += __expf(lg);
                    }
            }
        }
    }

    // reduce over the 16 column-lanes; lanes 0,16,32,48 hold disjoint rows
#pragma unroll
    for (int m = 1; m < 16; m <<= 1)
#pragma unroll
        for (int s = 0; s < 16; ++s) rsum[s] += __shfl_xor(rsum[s], m, 64);
    if (lane16 == 0) {
#pragma unroll
        for (int tr = 0; tr < 4; ++tr)
#pragma unroll
            for (int i = 0; i < 4; ++i)
                atomicAdd(&rowsum[wr * 64 + tr * 16 + quad * 4 + i], rsum[tr * 4 + i]);
    }
    __syncthreads();
    if (tid < 128) atomicAdd(&sumexp[(long)rb * 128 + tid], rowsum[tid]);
}

// ---------------- K3: target logit + CE + final reduce -------------------
__global__ __launch_bounds__(256) void k3_ce(const u16* __restrict__ A,
                                             const u16* __restrict__ OW,
                                             const float* __restrict__ outb,
                                             const float* __restrict__ sumexp,
                                             const int* __restrict__ y,
                                             float* __restrict__ out) {
    const int wave = threadIdx.x >> 6, lane = threadIdx.x & 63;
    const int r = blockIdx.x * 4 + wave;         // 0..32511
    const int t = r >> 8, b = r & 255;
    const int tgt = y[(t + 1) * BATCH + b];
    const u16* ar = A + (long)r * KP;
    const u16* wrow = OW + (long)tgt * KP;
    float s = 0.f;
#pragma unroll
    for (int i = 0; i < 5; ++i) {
        int k = lane + i * 64;                   // pad cols are zero
        float a = __uint_as_float(((unsigned)ar[k]) << 16);
        float w = __uint_as_float(((unsigned)wrow[k]) << 16);
        s += a * w;
    }
#pragma unroll
    for (int m = 1; m < 64; m <<= 1) s += __shfl_xor(s, m, 64);
    __shared__ float part[4];
    if (lane == 0) part[wave] = logf(sumexp[r]) - (s + outb[tgt]);
    __syncthreads();
    if (threadIdx.x == 0) {
        float tot = part[0] + part[1] + part[2] + part[3];
        atomicAdd(out, tot * (1.0f / 256.0f));
    }
}

// ---------------- launch --------------------------------------------------
extern "C" void kernel_launch(void* const* d_in, const int* in_sizes, int n_in,
                              void* d_out, int out_size, void* d_ws, size_t ws_size,
                              hipStream_t stream) {
    (void)in_sizes; (void)n_in; (void)out_size; (void)ws_size;
    const int*   x       = (const int*)d_in[0];
    const int*   y       = (const int*)d_in[1];
    const float* enc_emb = (const float*)d_in[2];
    const float* encW    = (const float*)d_in[3];
    const float* encb    = (const float*)d_in[4];
    const float* dec_emb = (const float*)d_in[5];
    const float* decW    = (const float*)d_in[6];
    const float* decb    = (const float*)d_in[7];
    const float* outW    = (const float*)d_in[8];
    const float* outb    = (const float*)d_in[9];

    char* ws = (char*)d_ws;
    __hip_bfloat16* owb = (__hip_bfloat16*)(ws + OW_OFF);
    __hip_bfloat16* A   = (__hip_bfloat16*)(ws + A_OFF);
    float* wte    = (float*)(ws + WTE_OFF);
    float* wtd    = (float*)(ws + WTD_OFF);
    float* sumexp = (float*)(ws + SE_OFF);

    hipMemsetAsync(sumexp, 0, SE_BYTES, stream);
    hipMemsetAsync(d_out, 0, sizeof(float), stream);

    long n0 = (long)NPAD * KP + 2L * H * KP;
    k0_prep<<<(int)((n0 + 255) / 256), 256, 0, stream>>>(outW, encW, decW, owb, wte, wtd);
    k1_rnn<<<64, 320, 0, stream>>>(x, y, enc_emb, dec_emb, encb, decb, wte, wtd, A);
    k2_gemm<<<254 * 8, 512, 0, stream>>>((const u16*)A, (const u16*)owb, outb, sumexp);
    k3_ce<<<8128, 256, 0, stream>>>((const u16*)A, (const u16*)owb, outb, sumexp, y, (float*)d_out);
}

// Round 2
// 1686.525 us; speedup vs baseline: 2.3585x; 2.3585x over previous
//
#include <hip/hip_runtime.h>
#include <hip/hip_bf16.h>
#include <stdint.h>

typedef unsigned short u16;
typedef short bf16x8 __attribute__((ext_vector_type(8)));
typedef float f32x4 __attribute__((ext_vector_type(4)));
typedef _Float16 f16x2 __attribute__((ext_vector_type(2)));
typedef _Float16 f16x8 __attribute__((ext_vector_type(8)));

#define H      300
#define KP     320          // K padded to multiple of 32
#define BATCH  256
#define NX     128
#define NY     128
#define VY     32000
#define NPAD   32768        // vocab padded to 8*16*256
#define MROWS  32512        // 127*256 decoder rows

// workspace layout (bytes)
#define OW_OFF   0UL
#define OW_BYTES ((unsigned long)NPAD * KP * 2)        // 20,971,520
#define A_OFF    (OW_OFF + OW_BYTES)
#define A_BYTES  ((unsigned long)MROWS * KP * 2)       // 20,807,680
#define WTE_OFF  (A_OFF + A_BYTES)
#define WT_BYTES ((unsigned long)H * KP * 4)           // 384,000
#define WTD_OFF  (WTE_OFF + WT_BYTES)
#define SE_OFF   (WTD_OFF + WT_BYTES)
#define SE_BYTES ((unsigned long)MROWS * 4)

typedef const __attribute__((address_space(1))) char* gp_t;
typedef __attribute__((address_space(3))) char* lp_t;

// ---------------- K0: prep (bf16-convert outW padded; transpose enc/dec W) --
__global__ __launch_bounds__(256) void k0_prep(const float* __restrict__ outW,
                                               const float* __restrict__ encW,
                                               const float* __restrict__ decW,
                                               __hip_bfloat16* __restrict__ owb,
                                               float* __restrict__ wte,
                                               float* __restrict__ wtd) {
    long id = (long)blockIdx.x * 256 + threadIdx.x;
    const long n1 = (long)NPAD * KP;
    if (id < n1) {
        int v = (int)(id / KP), k = (int)(id % KP);
        float f = (v < VY && k < H) ? outW[v * H + k] : 0.f;
        owb[id] = __float2bfloat16(f);
        return;
    }
    long id2 = id - n1;
    if (id2 < (long)H * KP) {                 // Wt_enc[k][j] = encW[j][k]
        int k = (int)(id2 / KP), j = (int)(id2 % KP);
        wte[id2] = (j < H) ? encW[j * H + k] : 0.f;
        return;
    }
    id2 -= (long)H * KP;
    if (id2 < (long)H * KP) {                 // Wt_dec
        int k = (int)(id2 / KP), j = (int)(id2 % KP);
        wtd[id2] = (j < H) ? decW[j * H + k] : 0.f;
    }
}

// ---------------- K1 v2: register-resident weights, 1 batch elem / block ----
// 256 blocks x 960 threads (15 waves). Thread (s=tid/320, j=tid%320) holds
// W[j][k-slice] as 52 packed fp16 pairs in VGPRs; h is fp16 in LDS (broadcast
// ds_read_b128). Per step: 52 v_dot2_f32_f16 + partial reduce over s=0..2.
// Embedding + index prefetched to hide the dependent global-load chain.
__global__ __launch_bounds__(960, 4) void k1_rnn(const int* __restrict__ x,
                                                 const int* __restrict__ y,
                                                 const float* __restrict__ enc_emb,
                                                 const float* __restrict__ dec_emb,
                                                 const float* __restrict__ encb,
                                                 const float* __restrict__ decb,
                                                 const float* __restrict__ wte,
                                                 const float* __restrict__ wtd,
                                                 __hip_bfloat16* __restrict__ A) {
    const int tid = threadIdx.x;
    const int s = tid / 320;          // 0..2, wave-uniform (320 = 5 waves)
    const int j = tid - s * 320;      // 0..319
    const int b = blockIdx.x;

    __shared__ __align__(16) _Float16 hh[320];   // h (fp16), pad j>=300 = 0
    __shared__ float part[960];

    for (int i = tid; i < 320; i += 960) hh[i] = (_Float16)0.f;

    const bool comb = (tid < 320);    // s==0 threads do the combine phase
    const float be = (comb && j < H) ? encb[j] : 0.f;
    const float bd = (comb && j < H) ? decb[j] : 0.f;

    // ---- preload encoder weights into registers (fp16 pairs) ----
    f16x2 w[52];
#pragma unroll
    for (int kk = 0; kk < 52; ++kk) {
        int k0 = 2 * (s * 52 + kk);
        float f0 = (k0 < H)     ? wte[k0 * KP + j]       : 0.f;
        float f1 = (k0 + 1 < H) ? wte[(k0 + 1) * KP + j] : 0.f;
        w[kk] = (f16x2){(_Float16)f0, (_Float16)f1};
    }

    // ---- encoder: 128 steps ----
    int idx_n = x[BATCH + b];
    float e_cur = 0.f;
    if (comb && j < H) e_cur = enc_emb[(long)x[b] * H + j];
    __syncthreads();

    const f16x8* hb8 = (const f16x8*)&hh[s * 104];

    for (int t = 0; t < NX; ++t) {
        int idx_n2 = x[min(t + 2, NX - 1) * BATCH + b];
        float e_nx = 0.f;
        if (comb && j < H && t + 1 < NX) e_nx = enc_emb[(long)idx_n * H + j];

        float p0 = 0.f, p1 = 0.f;
#pragma unroll
        for (int i = 0; i < 13; ++i) {
            f16x8 hv = hb8[i];
            f16x2 a0 = {hv[0], hv[1]}, a1 = {hv[2], hv[3]};
            f16x2 a2 = {hv[4], hv[5]}, a3 = {hv[6], hv[7]};
            p0 = __builtin_amdgcn_fdot2(w[4 * i + 0], a0, p0, false);
            p1 = __builtin_amdgcn_fdot2(w[4 * i + 1], a1, p1, false);
            p0 = __builtin_amdgcn_fdot2(w[4 * i + 2], a2, p0, false);
            p1 = __builtin_amdgcn_fdot2(w[4 * i + 3], a3, p1, false);
        }
        part[tid] = p0 + p1;
        __syncthreads();
        if (comb) {
            float v = part[j] + part[320 + j] + part[640 + j] + be + e_cur;
            hh[j] = (_Float16)fmaxf(v, 0.f);
        }
        __syncthreads();
        e_cur = e_nx; idx_n = idx_n2;
    }

    // ---- reload decoder weights ----
#pragma unroll
    for (int kk = 0; kk < 52; ++kk) {
        int k0 = 2 * (s * 52 + kk);
        float f0 = (k0 < H)     ? wtd[k0 * KP + j]       : 0.f;
        float f1 = (k0 + 1 < H) ? wtd[(k0 + 1) * KP + j] : 0.f;
        w[kk] = (f16x2){(_Float16)f0, (_Float16)f1};
    }

    // ---- decoder: 127 steps; write bf16 h rows into A ----
    idx_n = y[BATCH + b];
    e_cur = 0.f;
    if (comb && j < H) e_cur = dec_emb[(long)y[b] * H + j];

    for (int t = 0; t < NY - 1; ++t) {
        int idx_n2 = y[min(t + 2, NY - 1) * BATCH + b];
        float e_nx = 0.f;
        if (comb && j < H && t + 1 < NY - 1) e_nx = dec_emb[(long)idx_n * H + j];

        float p0 = 0.f, p1 = 0.f;
#pragma unroll
        for (int i = 0; i < 13; ++i) {
            f16x8 hv = hb8[i];
            f16x2 a0 = {hv[0], hv[1]}, a1 = {hv[2], hv[3]};
            f16x2 a2 = {hv[4], hv[5]}, a3 = {hv[6], hv[7]};
            p0 = __builtin_amdgcn_fdot2(w[4 * i + 0], a0, p0, false);
            p1 = __builtin_amdgcn_fdot2(w[4 * i + 1], a1, p1, false);
            p0 = __builtin_amdgcn_fdot2(w[4 * i + 2], a2, p0, false);
            p1 = __builtin_amdgcn_fdot2(w[4 * i + 3], a3, p1, false);
        }
        part[tid] = p0 + p1;
        __syncthreads();
        if (comb) {
            float v = part[j] + part[320 + j] + part[640 + j] + bd + e_cur;
            v = fmaxf(v, 0.f);
            hh[j] = (_Float16)v;
            A[(long)(t * BATCH + b) * KP + j] = __float2bfloat16(v);
        }
        __syncthreads();
        e_cur = e_nx; idx_n = idx_n2;
    }
}

// ---------------- K2: fused logits GEMM + exp row-sum --------------------
// grid = 254 rowblocks * 8 colgroups; colgroup == blockIdx%8 == XCD for L2
// locality of the 2.6MB outW slice. A tile (128x320 bf16) resident in LDS
// (row stride 328 to spread banks); B (256 cols x 32 k) double-buffered via
// global_load_lds width=16.
__global__ __launch_bounds__(512) void k2_gemm(const u16* __restrict__ A,
                                               const u16* __restrict__ OW,
                                               const float* __restrict__ outb,
                                               float* __restrict__ sumexp) {
    const int tid = threadIdx.x;
    const int lane = tid & 63, wave = tid >> 6;
    const int lane16 = lane & 15, quad = lane >> 4;
    const int wr = wave >> 2, wc = wave & 3;     // 2x4 wave grid, 64x64 tiles
    const int cg = blockIdx.x & 7;
    const int rb = blockIdx.x >> 3;

    __shared__ u16 Ald[128 * 328];
    __shared__ u16 Bld[2][8192];
    __shared__ float rowsum[128];
    if (tid < 128) rowsum[tid] = 0.f;

    // stage A tile once: 128 rows x 640B -> LDS stride 656B
    {
        const char* ag = (const char*)(A + (long)rb * 128 * KP);
#pragma unroll
        for (int i = 0; i < 10; ++i) {
            int t2 = i * 512 + tid;
            int row = t2 / 40, o = t2 % 40;
            uint4 v = *(const uint4*)(ag + row * 640 + o * 16);
            *(uint4*)((char*)Ald + row * 656 + o * 16) = v;
        }
    }

    const char* owg = (const char*)OW;
    const int colbase = cg * 4096;

    auto stage = [&](int it, int buf) {
        int ct = it / 10, ks = it - ct * 10;
        int v0 = colbase + ct * 256;
        int col = tid >> 2, kq = tid & 3;
        const char* g1 = owg + (long)(v0 + col) * 640 + ks * 64 + kq * 16;
        const char* g2 = owg + (long)(v0 + 128 + col) * 640 + ks * 64 + kq * 16;
        char* l1 = (char*)&Bld[buf][0] + tid * 16;
        char* l2 = (char*)&Bld[buf][0] + 8192 + tid * 16;
        __builtin_amdgcn_global_load_lds((gp_t)g1, (lp_t)l1, 16, 0, 0);
        __builtin_amdgcn_global_load_lds((gp_t)g2, (lp_t)l2, 16, 0, 0);
    };

    f32x4 acc[4][4];
    float rsum[16];
#pragma unroll
    for (int s = 0; s < 16; ++s) rsum[s] = 0.f;

    stage(0, 0);
    for (int it = 0; it < 160; ++it) {          // 16 col-tiles x 10 k-steps
        int ct = it / 10, ks = it - ct * 10;
        __syncthreads();                         // drains prev stage's loads
        if (it + 1 < 160) stage(it + 1, (it + 1) & 1);
        if (ks == 0) {
#pragma unroll
            for (int a = 0; a < 4; ++a)
#pragma unroll
                for (int b = 0; b < 4; ++b) acc[a][b] = (f32x4){0.f, 0.f, 0.f, 0.f};
        }
        const u16* Bb = &Bld[it & 1][0];
        bf16x8 af[4], bfr[4];
#pragma unroll
        for (int tr = 0; tr < 4; ++tr)
            af[tr] = *(const bf16x8*)&Ald[(wr * 64 + tr * 16 + lane16) * 328 + ks * 32 + quad * 8];
#pragma unroll
        for (int tc = 0; tc < 4; ++tc) {
            int col = wc * 64 + tc * 16 + lane16;
            bfr[tc] = *(const bf16x8*)&Bb[col * 32 + quad * 8];
        }
#pragma unroll
        for (int tr = 0; tr < 4; ++tr)
#pragma unroll
            for (int tc = 0; tc < 4; ++tc)
                acc[tr][tc] = __builtin_amdgcn_mfma_f32_16x16x32_bf16(af[tr], bfr[tc], acc[tr][tc], 0, 0, 0);

        if (ks == 9) {                           // epilogue for this col-tile
            int cb = colbase + ct * 256 + wc * 64;
#pragma unroll
            for (int tc = 0; tc < 4; ++tc) {
                int v = cb + tc * 16 + lane16;
                bool valid = v < VY;
                float ob = valid ? outb[v] : 0.f;
#pragma unroll
                for (int tr = 0; tr < 4; ++tr)
#pragma unroll
                    for (int i = 0; i < 4; ++i) {
                        float lg = acc[tr][tc][i] + ob;
                        if (valid) rsum[tr * 4 + i] += __expf(lg);
                    }
            }
        }
    }

    // reduce over the 16 column-lanes; lanes 0,16,32,48 hold disjoint rows
#pragma unroll
    for (int m = 1; m < 16; m <<= 1)
#pragma unroll
        for (int s = 0; s < 16; ++s) rsum[s] += __shfl_xor(rsum[s], m, 64);
    if (lane16 == 0) {
#pragma unroll
        for (int tr = 0; tr < 4; ++tr)
#pragma unroll
            for (int i = 0; i < 4; ++i)
                atomicAdd(&rowsum[wr * 64 + tr * 16 + quad * 4 + i], rsum[tr * 4 + i]);
    }
    __syncthreads();
    if (tid < 128) atomicAdd(&sumexp[(long)rb * 128 + tid], rowsum[tid]);
}

// ---------------- K3: target logit + CE + final reduce -------------------
__global__ __launch_bounds__(256) void k3_ce(const u16* __restrict__ A,
                                             const u16* __restrict__ OW,
                                             const float* __restrict__ outb,
                                             const float* __restrict__ sumexp,
                                             const int* __restrict__ y,
                                             float* __restrict__ out) {
    const int wave = threadIdx.x >> 6, lane = threadIdx.x & 63;
    const int r = blockIdx.x * 4 + wave;         // 0..32511
    const int t = r >> 8, b = r & 255;
    const int tgt = y[(t + 1) * BATCH + b];
    const u16* ar = A + (long)r * KP;
    const u16* wrow = OW + (long)tgt * KP;
    float s = 0.f;
#pragma unroll
    for (int i = 0; i < 5; ++i) {
        int k = lane + i * 64;                   // pad cols are zero
        float a = __uint_as_float(((unsigned)ar[k]) << 16);
        float w = __uint_as_float(((unsigned)wrow[k]) << 16);
        s += a * w;
    }
#pragma unroll
    for (int m = 1; m < 64; m <<= 1) s += __shfl_xor(s, m, 64);
    __shared__ float part[4];
    if (lane == 0) part[wave] = logf(sumexp[r]) - (s + outb[tgt]);
    __syncthreads();
    if (threadIdx.x == 0) {
        float tot = part[0] + part[1] + part[2] + part[3];
        atomicAdd(out, tot * (1.0f / 256.0f));
    }
}

// ---------------- launch --------------------------------------------------
extern "C" void kernel_launch(void* const* d_in, const int* in_sizes, int n_in,
                              void* d_out, int out_size, void* d_ws, size_t ws_size,
                              hipStream_t stream) {
    (void)in_sizes; (void)n_in; (void)out_size; (void)ws_size;
    const int*   x       = (const int*)d_in[0];
    const int*   y       = (const int*)d_in[1];
    const float* enc_emb = (const float*)d_in[2];
    const float* encW    = (const float*)d_in[3];
    const float* encb    = (const float*)d_in[4];
    const float* dec_emb = (const float*)d_in[5];
    const float* decW    = (const float*)d_in[6];
    const float* decb    = (const float*)d_in[7];
    const float* outW    = (const float*)d_in[8];
    const float* outb    = (const float*)d_in[9];

    char* ws = (char*)d_ws;
    __hip_bfloat16* owb = (__hip_bfloat16*)(ws + OW_OFF);
    __hip_bfloat16* A   = (__hip_bfloat16*)(ws + A_OFF);
    float* wte    = (float*)(ws + WTE_OFF);
    float* wtd    = (float*)(ws + WTD_OFF);
    float* sumexp = (float*)(ws + SE_OFF);

    hipMemsetAsync(sumexp, 0, SE_BYTES, stream);
    hipMemsetAsync(d_out, 0, sizeof(float), stream);

    long n0 = (long)NPAD * KP + 2L * H * KP;
    k0_prep<<<(int)((n0 + 255) / 256), 256, 0, stream>>>(outW, encW, decW, owb, wte, wtd);
    k1_rnn<<<256, 960, 0, stream>>>(x, y, enc_emb, dec_emb, encb, decb, wte, wtd, A);
    k2_gemm<<<254 * 8, 512, 0, stream>>>((const u16*)A, (const u16*)owb, outb, sumexp);
    k3_ce<<<8128, 256, 0, stream>>>((const u16*)A, (const u16*)owb, outb, sumexp, y, (float*)d_out);
}

// Round 4
// 1152.768 us; speedup vs baseline: 3.4506x; 1.4630x over previous
//
#include <hip/hip_runtime.h>
#include <hip/hip_bf16.h>
#include <stdint.h>

typedef unsigned short u16;
typedef unsigned char u8;
typedef float f32x4 __attribute__((ext_vector_type(4)));
typedef float f32x2 __attribute__((ext_vector_type(2)));
typedef _Float16 f16x2 __attribute__((ext_vector_type(2)));
typedef _Float16 f16x8 __attribute__((ext_vector_type(8)));

#define H      300
#define KP     320          // K padded (320 fp8 bytes per row)
#define BATCH  256
#define NX     128
#define NY     128
#define VY     32000
#define NPAD   32768        // vocab padded
#define MROWS  32512        // 127*256 decoder rows

// workspace layout (bytes)
#define OW8_OFF  0UL
#define OW8_BYTES ((unsigned long)NPAD * KP)           // 10,485,760
#define A8_OFF   (OW8_OFF + OW8_BYTES)
#define A8_BYTES ((unsigned long)MROWS * KP)           // 10,403,840
#define WTE_OFF  (A8_OFF + A8_BYTES)
#define WT_BYTES ((unsigned long)H * KP * 4)           // 384,000
#define WTD_OFF  (WTE_OFF + WT_BYTES)
#define SE_OFF   (WTD_OFF + WT_BYTES)
#define SE_BYTES ((unsigned long)MROWS * 4)

typedef const __attribute__((address_space(1))) char* gp_t;
typedef __attribute__((address_space(3))) char* lp_t;

// ---------------- K0: prep (fp8-convert outW padded; transpose enc/dec W) --
__global__ __launch_bounds__(256) void k0_prep(const float* __restrict__ outW,
                                               const float* __restrict__ encW,
                                               const float* __restrict__ decW,
                                               u8* __restrict__ ow8,
                                               float* __restrict__ wte,
                                               float* __restrict__ wtd) {
    long id = (long)blockIdx.x * 256 + threadIdx.x;
    const long n1 = (long)NPAD * KP / 4;         // u32 chunks of OW8
    if (id < n1) {
        int v = (int)(id / 80), k4 = (int)(id % 80) * 4;
        float4 f = {0.f, 0.f, 0.f, 0.f};
        if (v < VY && k4 < H) f = *(const float4*)&outW[(long)v * H + k4]; // k4<=296 -> full
        int w = __builtin_amdgcn_cvt_pk_fp8_f32(f.x, f.y, 0, false);
        w = __builtin_amdgcn_cvt_pk_fp8_f32(f.z, f.w, w, true);
        ((unsigned int*)ow8)[id] = (unsigned int)w;
        return;
    }
    long id2 = id - n1;
    if (id2 < (long)H * KP) {                 // Wt_enc[k][j] = encW[j][k]
        int k = (int)(id2 / KP), j = (int)(id2 % KP);
        wte[id2] = (j < H) ? encW[j * H + k] : 0.f;
        return;
    }
    id2 -= (long)H * KP;
    if (id2 < (long)H * KP) {                 // Wt_dec
        int k = (int)(id2 / KP), j = (int)(id2 % KP);
        wtd[id2] = (j < H) ? decW[j * H + k] : 0.f;
    }
}

// ---------------- K1: register-resident weights, 1 batch elem / block ----
// 256 blocks x 960 threads (15 waves). Thread (s=tid/320, j=tid%320) holds
// W[j][k-slice] as 52 packed fp16 pairs in VGPRs; h is fp16 in LDS (broadcast
// ds_read_b128). Decoder h rows written as fp8 to A8 for the vocab GEMM.
__global__ __launch_bounds__(960, 4) void k1_rnn(const int* __restrict__ x,
                                                 const int* __restrict__ y,
                                                 const float* __restrict__ enc_emb,
                                                 const float* __restrict__ dec_emb,
                                                 const float* __restrict__ encb,
                                                 const float* __restrict__ decb,
                                                 const float* __restrict__ wte,
                                                 const float* __restrict__ wtd,
                                                 u8* __restrict__ A8) {
    const int tid = threadIdx.x;
    const int s = tid / 320;          // 0..2, wave-uniform (320 = 5 waves)
    const int j = tid - s * 320;      // 0..319
    const int b = blockIdx.x;

    __shared__ __align__(16) _Float16 hh[320];   // h (fp16), pad j>=300 = 0
    __shared__ float part[960];

    for (int i = tid; i < 320; i += 960) hh[i] = (_Float16)0.f;

    const bool comb = (tid < 320);    // s==0 threads do the combine phase
    const float be = (comb && j < H) ? encb[j] : 0.f;
    const float bd = (comb && j < H) ? decb[j] : 0.f;

    // ---- preload encoder weights into registers (fp16 pairs) ----
    f16x2 w[52];
#pragma unroll
    for (int kk = 0; kk < 52; ++kk) {
        int k0 = 2 * (s * 52 + kk);
        float f0 = (k0 < H)     ? wte[k0 * KP + j]       : 0.f;
        float f1 = (k0 + 1 < H) ? wte[(k0 + 1) * KP + j] : 0.f;
        w[kk] = (f16x2){(_Float16)f0, (_Float16)f1};
    }

    // ---- encoder: 128 steps ----
    int idx_n = x[BATCH + b];
    float e_cur = 0.f;
    if (comb && j < H) e_cur = enc_emb[(long)x[b] * H + j];
    __syncthreads();

    const f16x8* hb8 = (const f16x8*)&hh[s * 104];

    for (int t = 0; t < NX; ++t) {
        int idx_n2 = x[min(t + 2, NX - 1) * BATCH + b];
        float e_nx = 0.f;
        if (comb && j < H && t + 1 < NX) e_nx = enc_emb[(long)idx_n * H + j];

        float p0 = 0.f, p1 = 0.f;
#pragma unroll
        for (int i = 0; i < 13; ++i) {
            f16x8 hv = hb8[i];
            f16x2 a0 = {hv[0], hv[1]}, a1 = {hv[2], hv[3]};
            f16x2 a2 = {hv[4], hv[5]}, a3 = {hv[6], hv[7]};
            p0 = __builtin_amdgcn_fdot2(w[4 * i + 0], a0, p0, false);
            p1 = __builtin_amdgcn_fdot2(w[4 * i + 1], a1, p1, false);
            p0 = __builtin_amdgcn_fdot2(w[4 * i + 2], a2, p0, false);
            p1 = __builtin_amdgcn_fdot2(w[4 * i + 3], a3, p1, false);
        }
        part[tid] = p0 + p1;
        __syncthreads();
        if (comb) {
            float v = part[j] + part[320 + j] + part[640 + j] + be + e_cur;
            hh[j] = (_Float16)fmaxf(v, 0.f);
        }
        __syncthreads();
        e_cur = e_nx; idx_n = idx_n2;
    }

    // ---- reload decoder weights ----
#pragma unroll
    for (int kk = 0; kk < 52; ++kk) {
        int k0 = 2 * (s * 52 + kk);
        float f0 = (k0 < H)     ? wtd[k0 * KP + j]       : 0.f;
        float f1 = (k0 + 1 < H) ? wtd[(k0 + 1) * KP + j] : 0.f;
        w[kk] = (f16x2){(_Float16)f0, (_Float16)f1};
    }

    // ---- decoder: 127 steps; write fp8 h rows into A8 ----
    idx_n = y[BATCH + b];
    e_cur = 0.f;
    if (comb && j < H) e_cur = dec_emb[(long)y[b] * H + j];

    for (int t = 0; t < NY - 1; ++t) {
        int idx_n2 = y[min(t + 2, NY - 1) * BATCH + b];
        float e_nx = 0.f;
        if (comb && j < H && t + 1 < NY - 1) e_nx = dec_emb[(long)idx_n * H + j];

        float p0 = 0.f, p1 = 0.f;
#pragma unroll
        for (int i = 0; i < 13; ++i) {
            f16x8 hv = hb8[i];
            f16x2 a0 = {hv[0], hv[1]}, a1 = {hv[2], hv[3]};
            f16x2 a2 = {hv[4], hv[5]}, a3 = {hv[6], hv[7]};
            p0 = __builtin_amdgcn_fdot2(w[4 * i + 0], a0, p0, false);
            p1 = __builtin_amdgcn_fdot2(w[4 * i + 1], a1, p1, false);
            p0 = __builtin_amdgcn_fdot2(w[4 * i + 2], a2, p0, false);
            p1 = __builtin_amdgcn_fdot2(w[4 * i + 3], a3, p1, false);
        }
        part[tid] = p0 + p1;
        __syncthreads();
        if (comb) {
            float v = part[j] + part[320 + j] + part[640 + j] + bd + e_cur;
            v = fmaxf(v, 0.f);
            hh[j] = (_Float16)v;
            int pk = __builtin_amdgcn_cvt_pk_fp8_f32(v, v, 0, false);
            A8[(long)(t * BATCH + b) * KP + j] = (u8)(pk & 0xff);
        }
        __syncthreads();
        e_cur = e_nx; idx_n = idx_n2;
    }
}

// ---------------- K2: fp8 logits GEMM + exp row-sum ----------------------
// grid = 254 rowblocks * 8 colgroups (colgroup==XCD for outW L2 locality).
// A tile 128x320 fp8 in LDS (stride 336, conflict-light b64 frag reads);
// B double-buffered 256colx32k fp8 via global_load_lds width=16.
// LDS ~59KB -> 2 blocks/CU; fragments 8B/lane -> half the LDS-pipe traffic.
__global__ __launch_bounds__(512, 4) void k2_gemm(const u8* __restrict__ A8,
                                                  const u8* __restrict__ OW8,
                                                  const float* __restrict__ outb,
                                                  float* __restrict__ sumexp) {
    const int tid = threadIdx.x;
    const int lane = tid & 63, wave = tid >> 6;
    const int lane16 = lane & 15, quad = lane >> 4;
    const int wr = wave >> 2, wc = wave & 3;     // 2x4 wave grid, 64x64 tiles
    const int cg = blockIdx.x & 7;
    const int rb = blockIdx.x >> 3;

    __shared__ u8 Ald[128 * 336];
    __shared__ u8 Bld[2][8192];
    __shared__ float rowsum[128];
    if (tid < 128) rowsum[tid] = 0.f;

    // stage A tile once: 128 rows x 320B -> LDS stride 336 (16B aligned)
    {
        const u8* ag = A8 + (long)rb * 128 * KP;
#pragma unroll
        for (int i = 0; i < 5; ++i) {
            int t2 = i * 512 + tid;
            int row = t2 / 20, o = t2 % 20;
            uint4 v = *(const uint4*)(ag + row * 320 + o * 16);
            *(uint4*)&Ald[row * 336 + o * 16] = v;
        }
    }

    const int colbase = cg * 4096;

    auto stage = [&](int it, int buf) {
        int ct = it / 10, ks = it - ct * 10;
        int v0 = colbase + ct * 256;
        int col = tid >> 1, kq = tid & 1;
        const u8* g = OW8 + (long)(v0 + col) * KP + ks * 32 + kq * 16;
        u8* l = &Bld[buf][0] + tid * 16;
        __builtin_amdgcn_global_load_lds((gp_t)g, (lp_t)l, 16, 0, 0);
    };

    f32x4 acc[4][4];
    float rsum[16];
#pragma unroll
    for (int s = 0; s < 16; ++s) rsum[s] = 0.f;

    stage(0, 0);
    for (int it = 0; it < 160; ++it) {          // 16 col-tiles x 10 k-steps
        int ct = it / 10, ks = it - ct * 10;
        __syncthreads();                         // drains prev stage's loads
        if (it + 1 < 160) stage(it + 1, (it + 1) & 1);
        if (ks == 0) {
#pragma unroll
            for (int a = 0; a < 4; ++a)
#pragma unroll
                for (int b = 0; b < 4; ++b) acc[a][b] = (f32x4){0.f, 0.f, 0.f, 0.f};
        }
        const u8* Bb = &Bld[it & 1][0];
        long af[4], bfr[4];
#pragma unroll
        for (int tr = 0; tr < 4; ++tr)
            af[tr] = *(const long*)&Ald[(wr * 64 + tr * 16 + lane16) * 336 + ks * 32 + quad * 8];
#pragma unroll
        for (int tc = 0; tc < 4; ++tc) {
            int col = wc * 64 + tc * 16 + lane16;
            bfr[tc] = *(const long*)&Bb[col * 32 + quad * 8];
        }
#pragma unroll
        for (int tr = 0; tr < 4; ++tr)
#pragma unroll
            for (int tc = 0; tc < 4; ++tc)
                acc[tr][tc] = __builtin_amdgcn_mfma_f32_16x16x32_fp8_fp8(af[tr], bfr[tc], acc[tr][tc], 0, 0, 0);

        if (ks == 9) {                           // epilogue for this col-tile
            int cb = colbase + ct * 256 + wc * 64;
#pragma unroll
            for (int tc = 0; tc < 4; ++tc) {
                int v = cb + tc * 16 + lane16;
                bool valid = v < VY;
                float ob = valid ? outb[v] : 0.f;
#pragma unroll
                for (int tr = 0; tr < 4; ++tr)
#pragma unroll
                    for (int i = 0; i < 4; ++i) {
                        float lg = acc[tr][tc][i] + ob;
                        if (valid) rsum[tr * 4 + i] += __expf(lg);
                    }
            }
        }
    }

    // reduce over the 16 column-lanes; lanes 0,16,32,48 hold disjoint rows
#pragma unroll
    for (int m = 1; m < 16; m <<= 1)
#pragma unroll
        for (int s = 0; s < 16; ++s) rsum[s] += __shfl_xor(rsum[s], m, 64);
    if (lane16 == 0) {
#pragma unroll
        for (int tr = 0; tr < 4; ++tr)
#pragma unroll
            for (int i = 0; i < 4; ++i)
                atomicAdd(&rowsum[wr * 64 + tr * 16 + quad * 4 + i], rsum[tr * 4 + i]);
    }
    __syncthreads();
    if (tid < 128) atomicAdd(&sumexp[(long)rb * 128 + tid], rowsum[tid]);
}

// ---------------- K3: target logit + CE + final reduce -------------------
__global__ __launch_bounds__(256) void k3_ce(const u8* __restrict__ A8,
                                             const u8* __restrict__ OW8,
                                             const float* __restrict__ outb,
                                             const float* __restrict__ sumexp,
                                             const int* __restrict__ y,
                                             float* __restrict__ out) {
    const int wave = threadIdx.x >> 6, lane = threadIdx.x & 63;
    const int r = blockIdx.x * 4 + wave;         // 0..32511
    const int t = r >> 8, b = r & 255;
    const int tgt = y[(t + 1) * BATCH + b];
    const unsigned int* ar = (const unsigned int*)(A8 + (long)r * KP);
    const unsigned int* wr_ = (const unsigned int*)(OW8 + (long)tgt * KP);
    float s = 0.f;
#pragma unroll
    for (int i = 0; i < 2; ++i) {
        int c = i * 64 + lane;                   // 80 u32 chunks per row
        if (c < 80) {
            unsigned int a4 = ar[c], w4 = wr_[c];
            f32x2 al = __builtin_amdgcn_cvt_pk_f32_fp8(a4, false);
            f32x2 ah = __builtin_amdgcn_cvt_pk_f32_fp8(a4, true);
            f32x2 wl = __builtin_amdgcn_cvt_pk_f32_fp8(w4, false);
            f32x2 wh = __builtin_amdgcn_cvt_pk_f32_fp8(w4, true);
            s += al[0] * wl[0] + al[1] * wl[1] + ah[0] * wh[0] + ah[1] * wh[1];
        }
    }
#pragma unroll
    for (int m = 1; m < 64; m <<= 1) s += __shfl_xor(s, m, 64);
    __shared__ float part[4];
    if (lane == 0) part[wave] = logf(sumexp[r]) - (s + outb[tgt]);
    __syncthreads();
    if (threadIdx.x == 0) {
        float tot = part[0] + part[1] + part[2] + part[3];
        atomicAdd(out, tot * (1.0f / 256.0f));
    }
}

// ---------------- launch --------------------------------------------------
extern "C" void kernel_launch(void* const* d_in, const int* in_sizes, int n_in,
                              void* d_out, int out_size, void* d_ws, size_t ws_size,
                              hipStream_t stream) {
    (void)in_sizes; (void)n_in; (void)out_size; (void)ws_size;
    const int*   x       = (const int*)d_in[0];
    const int*   y       = (const int*)d_in[1];
    const float* enc_emb = (const float*)d_in[2];
    const float* encW    = (const float*)d_in[3];
    const float* encb    = (const float*)d_in[4];
    const float* dec_emb = (const float*)d_in[5];
    const float* decW    = (const float*)d_in[6];
    const float* decb    = (const float*)d_in[7];
    const float* outW    = (const float*)d_in[8];
    const float* outb    = (const float*)d_in[9];

    char* ws = (char*)d_ws;
    u8* ow8  = (u8*)(ws + OW8_OFF);
    u8* A8   = (u8*)(ws + A8_OFF);
    float* wte    = (float*)(ws + WTE_OFF);
    float* wtd    = (float*)(ws + WTD_OFF);
    float* sumexp = (float*)(ws + SE_OFF);

    hipMemsetAsync(sumexp, 0, SE_BYTES, stream);
    hipMemsetAsync(d_out, 0, sizeof(float), stream);

    long n0 = (long)NPAD * KP / 4 + 2L * H * KP;
    k0_prep<<<(int)((n0 + 255) / 256), 256, 0, stream>>>(outW, encW, decW, ow8, wte, wtd);
    k1_rnn<<<256, 960, 0, stream>>>(x, y, enc_emb, dec_emb, encb, decb, wte, wtd, A8);
    k2_gemm<<<254 * 8, 512, 0, stream>>>(A8, ow8, outb, sumexp);
    k3_ce<<<8128, 256, 0, stream>>>(A8, ow8, outb, sumexp, y, (float*)d_out);
}